// Round 1
// 9087.334 us; speedup vs baseline: 1.0392x; 1.0392x over previous
//
#include <hip/hip_runtime.h>
#include <hip/hip_bf16.h>
#include <stdint.h>

// LSTM scan R6: tag-fused handshake — publish/poll/load collapse to one RTT.
// T=2048, B=64, DIN=H=512. Grid = 4 row-groups x 16 col-WGs = 64 WGs x 256 thr.
// Group g owns batch rows [16g,16g+16); WG (g,wc) owns h-cols [32wc,32wc+32).
// Weights in registers as MFMA B-frags. Waves 0,1: Wx K-halves; waves 2,3: Wh.
//
// R5 post-mortem: counters (MfmaUtil 2.4%, VALUBusy 4.1%, HBM 2.4%) => pure
// latency; per-step chain was ~3.5 serial coherent RTTs: store-ack vmcnt(0)
// -> slot publish -> slot poll detect -> separate h data load. R6 embeds a
// 16-bit epoch tag in every h dword: unit = (tag<<16)|bf16(h), tag = t+1.
// Dword stores are atomic (no tearing), tags monotone from zeroed buffer, so
// fresh <=> unit >= (t<<16) (only t or t-2 ever present; depth-2 ping-pong
// safety follows by the same induction as the old slot protocol).
//   producer: ONE global_store_dwordx2 sc0 sc1, fire-and-forget (no drain,
//             no slot store, no fence)
//   consumer: poll 16x global_load_dwordx4 sc0 sc1 (its own A-frags, tagged),
//             min-reduce 64 dwords, __all(min >= t<<16) -> data already in
//             registers on the breaking iteration.
// hbuf lives in a __device__ global (256 KiB) -> no ws-alias fallback, no
// cross-group final barrier.

#define TSTEPS 2048
#define BATCH  64
#define DINK   512
#define HHH    512
#define GB     4
#define GC     16
#define ROWS   16
#define NTHR   256

typedef __attribute__((ext_vector_type(8))) short    short8;
typedef __attribute__((ext_vector_type(4))) float    float4v;
typedef __attribute__((ext_vector_type(4))) int      int4v;
typedef __attribute__((ext_vector_type(2))) unsigned uint2v;

__device__ __attribute__((aligned(16))) unsigned g_hbuf[2 * BATCH * HHH];

static __device__ __forceinline__ unsigned short f2bf(float f) {
    union { float f; unsigned u; } v; v.f = f;
    unsigned u = v.u + 0x7FFFu + ((v.u >> 16) & 1u);   // RNE
    return (unsigned short)(u >> 16);
}
static __device__ __forceinline__ float sigm(float x) {
    return 1.0f / (1.0f + __expf(-x));
}
static __device__ __forceinline__ float tanh_fast(float x) {
    return 2.0f / (1.0f + __expf(-2.0f * x)) - 1.0f;
}
static __device__ __forceinline__ unsigned umin2(unsigned a, unsigned b) {
    return a < b ? a : b;
}

__global__ __launch_bounds__(NTHR, 1) void lstm_scan(
    const float* __restrict__ X,   // [T][64][512]
    const float* __restrict__ Wx,  // [512][2048]
    const float* __restrict__ bx,  // [2048]
    const float* __restrict__ Wh,  // [512][2048]
    const float* __restrict__ bh,  // [2048]
    float* out,                    // [2][64][512]
    unsigned* hbuf)                // 2 x [64][512] tagged dwords (zeroed)
{
    __shared__ float P[4][ROWS][132];
    __shared__ float cst[ROWS][33];
    __shared__ float hsum[ROWS][33];
    __shared__ float csum[ROWS][33];
    __shared__ float biasLds[128];

    const int tid  = threadIdx.x;
    const int wv   = tid >> 6;
    const int lane = tid & 63;
    const int l15  = lane & 15;
    const int quad = lane >> 4;
    const int g    = blockIdx.x >> 4;   // row group 0..3
    const int wc   = blockIdx.x & 15;   // col-WG 0..15
    const int rb   = g * ROWS;
    const int jbase = wc * 32;

    // ---- preload B fragments (weights, bf16) into registers ----
    const float* Wsrc = (wv < 2) ? Wx : Wh;
    const int k0 = (wv & 1) * 256;
    short8 bfrag[8][8];
    #pragma unroll
    for (int kc = 0; kc < 8; ++kc) {
        #pragma unroll
        for (int nt = 0; nt < 8; ++nt) {
            const int c    = nt * 16 + l15;
            const int gcol = (c >> 5) * HHH + jbase + (c & 31);
            const int kl   = k0 + kc * 32 + quad * 8;
            short8 tmp;
            #pragma unroll
            for (int j = 0; j < 8; ++j)
                tmp[j] = (short)f2bf(Wsrc[(size_t)(kl + j) * 2048 + gcol]);
            bfrag[kc][nt] = tmp;
        }
    }
    if (tid < 128) {
        const int gcol = (tid >> 5) * HHH + jbase + (tid & 31);
        biasLds[tid] = bx[gcol] + bh[gcol];
    }
    for (int i = tid; i < ROWS * 33; i += NTHR) {
        (&cst[0][0])[i] = 0.f; (&hsum[0][0])[i] = 0.f; (&csum[0][0])[i] = 0.f;
    }
    __syncthreads();

    const int r_ew  = tid >> 4;          // 0..15 (row in group)
    const int jj_ew = (tid & 15) * 2;    // 0,2,..,30

    for (int t = 0; t < TSTEPS; ++t) {
        const unsigned* hRu = hbuf + ((t + 1) & 1) * (BATCH * HHH);
        unsigned*       hWu = hbuf + (t & 1)       * (BATCH * HHH);

        float4v acc[8];
        #pragma unroll
        for (int nt = 0; nt < 8; ++nt) acc[nt] = (float4v){0.f, 0.f, 0.f, 0.f};

        if (wv < 2) {
            // ---- x path: 16 loads issued back-to-back, two-phase consume ----
            const float* xrow = X + (size_t)t * (BATCH * DINK)
                                  + (size_t)(rb + l15) * DINK + k0 + quad * 8;
            int4v xv[16];
            // kc stride = 32 floats = 128 B; pair at +0 / +16 B
            #define XLOAD(i, OFF) asm volatile( \
                "global_load_dwordx4 %0, %1, off offset:" OFF \
                : "=v"(xv[i]) : "v"(xrow))
            XLOAD( 0, "0");    XLOAD( 1, "16");
            XLOAD( 2, "128");  XLOAD( 3, "144");
            XLOAD( 4, "256");  XLOAD( 5, "272");
            XLOAD( 6, "384");  XLOAD( 7, "400");
            XLOAD( 8, "512");  XLOAD( 9, "528");
            XLOAD(10, "640");  XLOAD(11, "656");
            XLOAD(12, "768");  XLOAD(13, "784");
            XLOAD(14, "896");  XLOAD(15, "912");
            #undef XLOAD
            asm volatile("s_waitcnt vmcnt(8)"
                : "+v"(xv[0]), "+v"(xv[1]), "+v"(xv[2]), "+v"(xv[3]),
                  "+v"(xv[4]), "+v"(xv[5]), "+v"(xv[6]), "+v"(xv[7]));
            #pragma unroll
            for (int kc = 0; kc < 4; ++kc) {
                union { int4v i; float4v f; } a0, a1;
                a0.i = xv[2 * kc]; a1.i = xv[2 * kc + 1];
                short8 av;
                av[0] = (short)f2bf(a0.f[0]); av[1] = (short)f2bf(a0.f[1]);
                av[2] = (short)f2bf(a0.f[2]); av[3] = (short)f2bf(a0.f[3]);
                av[4] = (short)f2bf(a1.f[0]); av[5] = (short)f2bf(a1.f[1]);
                av[6] = (short)f2bf(a1.f[2]); av[7] = (short)f2bf(a1.f[3]);
                #pragma unroll
                for (int nt = 0; nt < 8; ++nt)
                    acc[nt] = __builtin_amdgcn_mfma_f32_16x16x32_bf16(
                        av, bfrag[kc][nt], acc[nt], 0, 0, 0);
            }
            asm volatile("s_waitcnt vmcnt(0)"
                : "+v"(xv[8]),  "+v"(xv[9]),  "+v"(xv[10]), "+v"(xv[11]),
                  "+v"(xv[12]), "+v"(xv[13]), "+v"(xv[14]), "+v"(xv[15]));
            #pragma unroll
            for (int kc = 4; kc < 8; ++kc) {
                union { int4v i; float4v f; } a0, a1;
                a0.i = xv[2 * kc]; a1.i = xv[2 * kc + 1];
                short8 av;
                av[0] = (short)f2bf(a0.f[0]); av[1] = (short)f2bf(a0.f[1]);
                av[2] = (short)f2bf(a0.f[2]); av[3] = (short)f2bf(a0.f[3]);
                av[4] = (short)f2bf(a1.f[0]); av[5] = (short)f2bf(a1.f[1]);
                av[6] = (short)f2bf(a1.f[2]); av[7] = (short)f2bf(a1.f[3]);
                #pragma unroll
                for (int nt = 0; nt < 8; ++nt)
                    acc[nt] = __builtin_amdgcn_mfma_f32_16x16x32_bf16(
                        av, bfrag[kc][nt], acc[nt], 0, 0, 0);
            }
        } else {
            // ---- h path: poll tagged data directly; detect == load ----
            const int hc0 = (wv - 2) * 256;
            const unsigned* hrow = hRu + (size_t)(rb + l15) * HHH + hc0 + quad * 8;
            const unsigned thr = (unsigned)t << 16;
            int4v hv[16];
            for (;;) {
                // kc stride = 32 dwords = 128 B; pair at +0 / +16 B
                #define HLOAD(i, OFF) asm volatile( \
                    "global_load_dwordx4 %0, %1, off offset:" OFF " sc0 sc1" \
                    : "=v"(hv[i]) : "v"(hrow))
                HLOAD( 0, "0");    HLOAD( 1, "16");
                HLOAD( 2, "128");  HLOAD( 3, "144");
                HLOAD( 4, "256");  HLOAD( 5, "272");
                HLOAD( 6, "384");  HLOAD( 7, "400");
                HLOAD( 8, "512");  HLOAD( 9, "528");
                HLOAD(10, "640");  HLOAD(11, "656");
                HLOAD(12, "768");  HLOAD(13, "784");
                HLOAD(14, "896");  HLOAD(15, "912");
                #undef HLOAD
                asm volatile("s_waitcnt vmcnt(0)"
                    : "+v"(hv[0]),  "+v"(hv[1]),  "+v"(hv[2]),  "+v"(hv[3]),
                      "+v"(hv[4]),  "+v"(hv[5]),  "+v"(hv[6]),  "+v"(hv[7]),
                      "+v"(hv[8]),  "+v"(hv[9]),  "+v"(hv[10]), "+v"(hv[11]),
                      "+v"(hv[12]), "+v"(hv[13]), "+v"(hv[14]), "+v"(hv[15]));
                if (t == 0) break;                 // zeroed buffer == h(0)=0
                unsigned m = 0xFFFFFFFFu;
                #pragma unroll
                for (int i = 0; i < 16; ++i) {
                    union { int4v v; unsigned u[4]; } q; q.v = hv[i];
                    m = umin2(m, umin2(umin2(q.u[0], q.u[1]),
                                       umin2(q.u[2], q.u[3])));
                }
                if (__all((int)(m >= thr))) break;
            }
            #pragma unroll
            for (int kc = 0; kc < 8; ++kc) {
                union { int4v v; unsigned u[4]; } a0, a1;
                a0.v = hv[2 * kc]; a1.v = hv[2 * kc + 1];
                short8 av;
                av[0] = (short)(a0.u[0] & 0xFFFFu); av[1] = (short)(a0.u[1] & 0xFFFFu);
                av[2] = (short)(a0.u[2] & 0xFFFFu); av[3] = (short)(a0.u[3] & 0xFFFFu);
                av[4] = (short)(a1.u[0] & 0xFFFFu); av[5] = (short)(a1.u[1] & 0xFFFFu);
                av[6] = (short)(a1.u[2] & 0xFFFFu); av[7] = (short)(a1.u[3] & 0xFFFFu);
                #pragma unroll
                for (int nt = 0; nt < 8; ++nt)
                    acc[nt] = __builtin_amdgcn_mfma_f32_16x16x32_bf16(
                        av, bfrag[kc][nt], acc[nt], 0, 0, 0);
            }
        }

        // K-partials to LDS (C layout: row = quad*4+r, col = nt*16+l15)
        #pragma unroll
        for (int nt = 0; nt < 8; ++nt) {
            const int col = nt * 16 + l15;
            #pragma unroll
            for (int r = 0; r < 4; ++r)
                P[wv][quad * 4 + r][col] = acc[nt][r];
        }
        __syncthreads();

        // elementwise: thread -> (row r_ew, h-cols jj_ew, jj_ew+1)
        {
            float h2[2];
            #pragma unroll
            for (int e = 0; e < 2; ++e) {
                const int jj = jj_ew + e;
                const int r  = r_ew;
                float gi = biasLds[jj]      + P[0][r][jj]      + P[1][r][jj]      + P[2][r][jj]      + P[3][r][jj];
                float gf = biasLds[32 + jj] + P[0][r][32 + jj] + P[1][r][32 + jj] + P[2][r][32 + jj] + P[3][r][32 + jj];
                float go = biasLds[64 + jj] + P[0][r][64 + jj] + P[1][r][64 + jj] + P[2][r][64 + jj] + P[3][r][64 + jj];
                float gz = biasLds[96 + jj] + P[0][r][96 + jj] + P[1][r][96 + jj] + P[2][r][96 + jj] + P[3][r][96 + jj];
                const float c_old = cst[r][jj];
                const float cn = sigm(gi) * tanh_fast(gz) + sigm(gf) * c_old;
                const float hn = sigm(go) * tanh_fast(cn);
                cst[r][jj]  = cn;
                csum[r][jj] += cn;
                hsum[r][jj] += hn;
                h2[e] = hn;
            }
            // fire-and-forget tagged publish: one dwordx2, each dword is a
            // self-contained (tag<<16)|bf16 unit -> no ack, no slot, no fence
            const unsigned tagW = ((unsigned)(t + 1)) << 16;
            uint2v pk;
            pk[0] = tagW | (unsigned)f2bf(h2[0]);
            pk[1] = tagW | (unsigned)f2bf(h2[1]);
            unsigned* dst = hWu + (size_t)(rb + r_ew) * HHH + jbase + jj_ew;
            asm volatile("global_store_dwordx2 %0, %1, off sc0 sc1"
                         :: "v"(dst), "v"(pk) : "memory");
        }

        __syncthreads();   // protect P for next iteration's writes
    }

    const float invT = 1.0f / (float)TSTEPS;
    {
        const int b = rb + r_ew;
        const size_t o0 = (size_t)b * HHH + jbase + jj_ew;
        out[o0]                              = hsum[r_ew][jj_ew] * invT;
        out[o0 + 1]                          = hsum[r_ew][jj_ew + 1] * invT;
        out[(size_t)(BATCH * HHH) + o0]      = csum[r_ew][jj_ew] * invT;
        out[(size_t)(BATCH * HHH) + o0 + 1]  = csum[r_ew][jj_ew + 1] * invT;
    }
}

extern "C" void kernel_launch(void* const* d_in, const int* in_sizes, int n_in,
                              void* d_out, int out_size, void* d_ws, size_t ws_size,
                              hipStream_t stream) {
    (void)in_sizes; (void)n_in; (void)out_size;
    const float* X  = (const float*)d_in[0];
    const float* Wx = (const float*)d_in[1];
    const float* bx = (const float*)d_in[2];
    const float* Wh = (const float*)d_in[3];
    const float* bh = (const float*)d_in[4];
    float* out = (float*)d_out;

    const size_t HBUF_BYTES = sizeof(unsigned) * 2 * BATCH * HHH;   // 256 KiB

    static void* sym = nullptr;
    if (!sym) hipGetSymbolAddress(&sym, HIP_SYMBOL(g_hbuf));
    unsigned* hbuf = sym ? (unsigned*)sym
                         : (ws_size >= HBUF_BYTES ? (unsigned*)d_ws : (unsigned*)d_out);

    // tags must restart from 0 each replay (monotone-threshold freshness check)
    hipMemsetAsync(hbuf, 0, HBUF_BYTES, stream);
    lstm_scan<<<GB * GC, NTHR, 0, stream>>>(X, Wx, bx, Wh, bh, out, hbuf);
}